// Round 3
// baseline (426.336 us; speedup 1.0000x reference)
//
#include <hip/hip_runtime.h>
#include <stdint.h>

typedef __bf16 bf16;
typedef __bf16 bf16x8 __attribute__((ext_vector_type(8)));
typedef float f32x4 __attribute__((ext_vector_type(4)));

#define AS1 __attribute__((address_space(1)))
#define AS3 __attribute__((address_space(3)))

// Sizes (fixed by the problem)
// x: [4,2048,1024] f32, W: [1024,3072] f32, out: [4,2048,1024] f32
// ws layout (bytes):
//   xb  [8192][1024] bf16   @ 0          (16,777,216)
//   wt  [3072][1024] bf16   @ 16777216   ( 6,291,456)
//   kb  [64][2048][64] bf16 @ 23068672   (16,777,216)
//   qb  [64][2048][64] bf16 @ 39845888   (16,777,216)  (pre-scaled by log2e/32)
//   vt  [64][64][2048] bf16 @ 56623104   (16,777,216)
// total 73,400,320 B
//
// Softmax runs in base-2: logits are scaled by log2e (folded into qb and the
// ALiBi slope), exp = v_exp_f32 directly.

// ---------------- x -> bf16 ----------------
__global__ void cvt_x_kernel(const float* __restrict__ x, bf16* __restrict__ xb) {
    int i = blockIdx.x * 256 + threadIdx.x;     // 4096*256 threads, 8 elems each
    const float4* x4 = (const float4*)x;
    float4 a = x4[i * 2];
    float4 b = x4[i * 2 + 1];
    bf16x8 o;
    o[0] = (bf16)a.x; o[1] = (bf16)a.y; o[2] = (bf16)a.z; o[3] = (bf16)a.w;
    o[4] = (bf16)b.x; o[5] = (bf16)b.y; o[6] = (bf16)b.z; o[7] = (bf16)b.w;
    *(bf16x8*)(xb + (size_t)i * 8) = o;
}

// ---------------- W [1024][3072] f32 -> Wt [3072][1024] bf16 ----------------
__global__ void cvt_w_kernel(const float* __restrict__ w, bf16* __restrict__ wt) {
    __shared__ float tile[32][33];
    int nt = blockIdx.x, kt = blockIdx.y;       // 96 x 32
    int tx = threadIdx.x, ty = threadIdx.y;     // 32 x 8
#pragma unroll
    for (int j = 0; j < 4; ++j)
        tile[ty + j * 8][tx] = w[(size_t)(kt * 32 + ty + j * 8) * 3072 + nt * 32 + tx];
    __syncthreads();
#pragma unroll
    for (int j = 0; j < 4; ++j)
        wt[(size_t)(nt * 32 + ty + j * 8) * 1024 + kt * 32 + tx] = (bf16)tile[tx][ty + j * 8];
}

// ---------------- GEMM: kqv = xb @ wt^T, scatter to kb/qb/vt ----------------
// 128x128 tile, BK=32, 256 thr (4 waves, 2x2 of 64x64), m97-style
__global__ __launch_bounds__(256) void gemm_kqv_kernel(
    const bf16* __restrict__ xb, const bf16* __restrict__ wt,
    bf16* __restrict__ kb, bf16* __restrict__ qb, bf16* __restrict__ vt) {
    __shared__ bf16 As[2][128 * 32];
    __shared__ bf16 Bs[2][128 * 32];
    int bid = blockIdx.x;
    int bm = bid / 24, bn = bid % 24;
    int m0 = bm * 128, n0 = bn * 128;
    int t = threadIdx.x;
    int lane = t & 63, wid = t >> 6;
    int g = lane >> 4, l15 = lane & 15;
    int wr = wid >> 1, wc = wid & 1;

    f32x4 acc[4][4] = {};

    auto stageAB = [&](int ks, int buf) {
        int k0 = ks * 32;
#pragma unroll
        for (int c = 0; c < 2; ++c) {
            int slot = c * 256 + t;
            int row = slot >> 2, kk = (slot & 3) * 8;
            __builtin_amdgcn_global_load_lds(
                (const AS1 void*)(xb + (size_t)(m0 + row) * 1024 + k0 + kk),
                (AS3 void*)(&As[buf][slot * 8]), 16, 0, 0);
        }
#pragma unroll
        for (int c = 0; c < 2; ++c) {
            int slot = c * 256 + t;
            int row = slot >> 2, kk = (slot & 3) * 8;
            __builtin_amdgcn_global_load_lds(
                (const AS1 void*)(wt + (size_t)(n0 + row) * 1024 + k0 + kk),
                (AS3 void*)(&Bs[buf][slot * 8]), 16, 0, 0);
        }
    };

    stageAB(0, 0);
    for (int ks = 0; ks < 32; ++ks) {
        __syncthreads();                 // stage(ks) complete; prev reads done
        if (ks + 1 < 32) stageAB(ks + 1, (ks + 1) & 1);
        const bf16* Ab = As[ks & 1];
        const bf16* Bb = Bs[ks & 1];
        bf16x8 af[4], bfr[4];
#pragma unroll
        for (int mi = 0; mi < 4; ++mi)
            af[mi] = *(const bf16x8*)(Ab + (wr * 64 + mi * 16 + l15) * 32 + g * 8);
#pragma unroll
        for (int ni = 0; ni < 4; ++ni)
            bfr[ni] = *(const bf16x8*)(Bb + (wc * 64 + ni * 16 + l15) * 32 + g * 8);
#pragma unroll
        for (int mi = 0; mi < 4; ++mi)
#pragma unroll
            for (int ni = 0; ni < 4; ++ni)
                acc[mi][ni] = __builtin_amdgcn_mfma_f32_16x16x32_bf16(
                    af[mi], bfr[ni], acc[mi][ni], 0, 0, 0);
    }

    // epilogue: D layout col=lane&15, row=(lane>>4)*4+reg
    int tsel = n0 >> 10;  // uniform per block: 0=k,1=q,2=v
#pragma unroll
    for (int mi = 0; mi < 4; ++mi) {
#pragma unroll
        for (int ni = 0; ni < 4; ++ni) {
#pragma unroll
            for (int r = 0; r < 4; ++r) {
                int row = m0 + wr * 64 + mi * 16 + g * 4 + r;
                int col = n0 + wc * 64 + ni * 16 + l15;
                int b = row >> 11, s = row & 2047;
                int cc = col & 1023;
                int h = cc >> 6, d = cc & 63;
                int bh = b * 16 + h;
                float v = acc[mi][ni][r];
                if (tsel == 0)      kb[((size_t)bh * 2048 + s) * 64 + d] = (bf16)v;
                else if (tsel == 1) qb[((size_t)bh * 2048 + s) * 64 + d] = (bf16)(v * 0.0450842503f); // log2e/32
                else                vt[((size_t)bh * 64 + d) * 2048 + s] = (bf16)v;
            }
        }
    }
}

// ---------------- Flash attention with ALiBi (base-2 softmax) ----------------
// grid: 64 bh * 16 qtiles; block 256 (4 waves x 32 q-rows); KV tile 64
__global__ __launch_bounds__(256) void attn_kernel(
    const bf16* __restrict__ qb, const bf16* __restrict__ kb,
    const bf16* __restrict__ vt, float* __restrict__ out) {
    __shared__ bf16 Kl[2][64 * 64];
    __shared__ bf16 Vl[2][64 * 64];
    __shared__ bf16 Pl[4][32 * 64];
    int bid = blockIdx.x;
    int bh = bid >> 4, qt = bid & 15;
    int b = bh >> 4, h = bh & 15;
    int t = threadIdx.x, lane = t & 63, wid = t >> 6;
    int g = lane >> 4, l15 = lane & 15;
    int q0 = qt * 128 + wid * 32;
    // ALiBi slope 2^{-(h+1)/2}, scaled by log2e for base-2 softmax
    float mh2 = exp2f(-0.5f * (float)(h + 1)) * 1.44269504f;

    const bf16* Qp = qb + ((size_t)bh * 2048 + q0) * 64;
    const bf16* Kp = kb + (size_t)bh * 2048 * 64;
    const bf16* Vp = vt + (size_t)bh * 64 * 2048;

    // Q fragments hoisted to registers (A-frag: row=l15, k=g*8+i)
    bf16x8 qf[2][2];
#pragma unroll
    for (int qi = 0; qi < 2; ++qi)
#pragma unroll
        for (int kk = 0; kk < 2; ++kk)
            qf[qi][kk] = *(const bf16x8*)(Qp + (size_t)(qi * 16 + l15) * 64 + kk * 32 + g * 8);

    f32x4 oacc[2][4] = {};
    float mrun[2][4], lrun[2][4];
#pragma unroll
    for (int qi = 0; qi < 2; ++qi)
#pragma unroll
        for (int r = 0; r < 4; ++r) { mrun[qi][r] = -3.0e38f; lrun[qi][r] = 0.f; }

    float colb[4];
#pragma unroll
    for (int ji = 0; ji < 4; ++ji) colb[ji] = mh2 * (float)(ji * 16 + l15);

    // stage K tile [64 j][64 d] and V^T tile [64 d][64 j], source-side XOR swizzle
    auto stageKV = [&](int tile, int buf) {
        int j0 = tile * 64;
#pragma unroll
        for (int c = 0; c < 2; ++c) {
            int slot = c * 256 + t;
            int row = slot >> 3;
            int cs = (slot & 7) ^ (row & 7);
            __builtin_amdgcn_global_load_lds(
                (const AS1 void*)(Kp + (size_t)(j0 + row) * 64 + cs * 8),
                (AS3 void*)(&Kl[buf][slot * 8]), 16, 0, 0);
        }
#pragma unroll
        for (int c = 0; c < 2; ++c) {
            int slot = c * 256 + t;
            int row = slot >> 3;
            int cs = (slot & 7) ^ (row & 7);
            __builtin_amdgcn_global_load_lds(
                (const AS1 void*)(Vp + (size_t)row * 2048 + j0 + cs * 8),
                (AS3 void*)(&Vl[buf][slot * 8]), 16, 0, 0);
        }
    };

    stageKV(0, 0);
    bf16* Pw = Pl[wid];

    for (int tile = 0; tile < 32; ++tile) {
        __syncthreads();
        if (tile + 1 < 32) stageKV(tile + 1, (tile + 1) & 1);
        const bf16* Kb = Kl[tile & 1];
        const bf16* Vb = Vl[tile & 1];

        // S2 = (Q*log2e/32) K^T   (D: row=q=(g*4+r)+qi*16, col=j=ji*16+l15)
        f32x4 sc[2][4] = {};
#pragma unroll
        for (int ji = 0; ji < 4; ++ji) {
#pragma unroll
            for (int kk = 0; kk < 2; ++kk) {
                int row = ji * 16 + l15;
                int c16 = (kk * 4 + g) ^ (row & 7);
                bf16x8 kf = *(const bf16x8*)(Kb + row * 64 + c16 * 8);
#pragma unroll
                for (int qi = 0; qi < 2; ++qi)
                    sc[qi][ji] = __builtin_amdgcn_mfma_f32_16x16x32_bf16(
                        qf[qi][kk], kf, sc[qi][ji], 0, 0, 0);
            }
        }

        // + ALiBi*log2e (the -m*i row term is softmax-invariant; add only m*j)
        float tb = mh2 * (float)(tile * 64);
#pragma unroll
        for (int qi = 0; qi < 2; ++qi) {
#pragma unroll
            for (int ji = 0; ji < 4; ++ji) {
                float add = tb + colb[ji];
#pragma unroll
                for (int r = 0; r < 4; ++r) sc[qi][ji][r] += add;
            }
            // online softmax per q-row (row lives in a 16-lane group), base-2
#pragma unroll
            for (int r = 0; r < 4; ++r) {
                float mx = fmaxf(fmaxf(sc[qi][0][r], sc[qi][1][r]),
                                 fmaxf(sc[qi][2][r], sc[qi][3][r]));
#pragma unroll
                for (int m = 1; m < 16; m <<= 1) mx = fmaxf(mx, __shfl_xor(mx, m));
                float mnew = fmaxf(mrun[qi][r], mx);
                float corr = __builtin_amdgcn_exp2f(mrun[qi][r] - mnew);
                mrun[qi][r] = mnew;
                lrun[qi][r] *= corr;
#pragma unroll
                for (int di = 0; di < 4; ++di) oacc[qi][di][r] *= corr;
                float sum = 0.f;
#pragma unroll
                for (int ji = 0; ji < 4; ++ji) {
                    float p = __builtin_amdgcn_exp2f(sc[qi][ji][r] - mnew);
                    sc[qi][ji][r] = p;
                    sum += p;
                }
#pragma unroll
                for (int m = 1; m < 16; m <<= 1) sum += __shfl_xor(sum, m);
                lrun[qi][r] += sum;
            }
        }

        // P -> wave-private LDS (bf16, swizzled), then reload as A-fragments
#pragma unroll
        for (int qi = 0; qi < 2; ++qi)
#pragma unroll
            for (int r = 0; r < 4; ++r) {
                int row = qi * 16 + g * 4 + r;
                int rs = row & 7;
#pragma unroll
                for (int ji = 0; ji < 4; ++ji) {
                    int col = ji * 16 + l15;
                    int addr = row * 64 + (((col >> 3) ^ rs) * 8) + (col & 7);
                    Pw[addr] = (bf16)sc[qi][ji][r];
                }
            }

        // O += P @ V  (B-frag from V^T tile: col=d, k=j)
#pragma unroll
        for (int kk = 0; kk < 2; ++kk) {
            bf16x8 pf[2];
#pragma unroll
            for (int qi = 0; qi < 2; ++qi) {
                int row = qi * 16 + l15;
                int c16 = (kk * 4 + g) ^ (row & 7);
                pf[qi] = *(const bf16x8*)(Pw + row * 64 + c16 * 8);
            }
#pragma unroll
            for (int di = 0; di < 4; ++di) {
                int row = di * 16 + l15;
                int c16 = (kk * 4 + g) ^ (row & 7);
                bf16x8 vf = *(const bf16x8*)(Vb + row * 64 + c16 * 8);
#pragma unroll
                for (int qi = 0; qi < 2; ++qi)
                    oacc[qi][di] = __builtin_amdgcn_mfma_f32_16x16x32_bf16(
                        pf[qi], vf, oacc[qi][di], 0, 0, 0);
            }
        }
    }

    // epilogue: out[b][s][h*64+d] = O / l
#pragma unroll
    for (int qi = 0; qi < 2; ++qi) {
#pragma unroll
        for (int r = 0; r < 4; ++r) {
            float inv = 1.0f / lrun[qi][r];
            int s = q0 + qi * 16 + g * 4 + r;
            float* op = out + ((size_t)b * 2048 + s) * 1024 + h * 64;
#pragma unroll
            for (int di = 0; di < 4; ++di)
                op[di * 16 + l15] = oacc[qi][di][r] * inv;
        }
    }
}

extern "C" void kernel_launch(void* const* d_in, const int* in_sizes, int n_in,
                              void* d_out, int out_size, void* d_ws, size_t ws_size,
                              hipStream_t stream) {
    (void)in_sizes; (void)n_in; (void)out_size; (void)ws_size;
    const float* x = (const float*)d_in[0];
    const float* w = (const float*)d_in[1];
    float* out = (float*)d_out;
    char* ws = (char*)d_ws;
    bf16* xb = (bf16*)(ws);
    bf16* wt = (bf16*)(ws + 16777216);
    bf16* kb = (bf16*)(ws + 23068672);
    bf16* qb = (bf16*)(ws + 39845888);
    bf16* vt = (bf16*)(ws + 56623104);

    cvt_x_kernel<<<4096, 256, 0, stream>>>(x, xb);
    cvt_w_kernel<<<dim3(96, 32), dim3(32, 8), 0, stream>>>(w, wt);
    gemm_kqv_kernel<<<1536, 256, 0, stream>>>(xb, wt, kb, qb, vt);
    attn_kernel<<<1024, 256, 0, stream>>>(qb, kb, vt, out);
}